// Round 10
// baseline (2226.232 us; speedup 1.0000x reference)
//
#include <hip/hip_runtime.h>
#include <hip/hip_bf16.h>

// MultiViewFusion — SELF-CHECKING diagnostic round.
// Rounds 6-9 fail at absmax 0.13-0.17 invariant under precision (bf16/f16/
// hi-lo-split) and under scalar-vs-MFMA second half (round 9). This kernel
// computes S twice: (A) round-9-verbatim MFMA stages 1/2, (B) independent
// scalar-f32 path (global x, f32 weights, different thread map). Output is
// driven by (B); each MFMA thread compares (A) vs (B) and on mismatch writes
// an encoded coordinate P = 10000*stage + 1000*lk8 + 100*reg + 10*nt +
// 0.1*lrow into out. absmax decodes: <=0.03 pass | ~0.15 MFMA==scalar but
// wrong anyway | >=10000 MFMA!=scalar at the encoded coords.

namespace {

typedef __attribute__((ext_vector_type(8))) short short8v;
typedef __attribute__((ext_vector_type(4))) float floatx4;

// workspace byte offsets
constexpr int OFF_CW  = 0;        // f32 CWt[4][128][128]
constexpr int OFF_CB  = 262144;   // f32 cv[4][128]
constexpr int OFF_BT  = 264192;   // f32 bT[256]  [ts|uc]
constexpr int OFF_BU  = 265216;   // f32 bU[256]  [tc|us]
constexpr int OFF_MTH = 266240;   // bf16 M_text hi packed [96][256][8]
constexpr int OFF_MTL = 659456;   // bf16 M_text lo
constexpr int OFF_MUH = 1052672;  // bf16 M_user hi packed [32][256][8]
constexpr int OFF_MUL = 1183744;  // bf16 M_user lo
constexpr int OFF_GW4 = 1314816;  // f32 gate W [64][256][4] (cols tg|ug)
constexpr int OFF_FW4 = 1576960;  // f32 ff  W  [64][256][4]
constexpr int OFF_MT4 = 1839104;  // f32 M_text [192][256][4]
constexpr int OFF_MU4 = 2625536;  // f32 M_user [64][256][4]
// end 2887680 (~2.9 MB)

__device__ inline unsigned short f2b(float f) {
  __hip_bfloat16 h = __float2bfloat16(f);
  return __builtin_bit_cast(unsigned short, h);
}
__device__ inline float b2f(unsigned short u) {
  unsigned int v = ((unsigned int)u) << 16;
  return __builtin_bit_cast(float, v);
}
__device__ inline void split2(float v, unsigned short& h, unsigned short& l) {
  h = f2b(v);
  l = f2b(v - b2f(h));
}

// ---------------- precompute ----------------

__global__ void k_combine(const float* __restrict__ ipw, const float* __restrict__ opw,
                          char* __restrict__ wsb) {
  float* cw = (float*)(wsb + OFF_CW);
  int n = blockIdx.x * 256 + threadIdx.x;
  int i = n >> 14, o = (n >> 7) & 127, d = n & 127;
  const float* op = opw + i * 16384 + o * 128;
  const float* iv = ipw + i * 49152 + 256 * 128 + d;
  float s = 0.f;
#pragma unroll 4
  for (int m = 0; m < 128; ++m) s = fmaf(op[m], iv[m * 128], s);
  cw[i * 16384 + d * 128 + o] = s;
}

__global__ void k_combine_bias(const float* __restrict__ ipb, const float* __restrict__ opb,
                               const float* __restrict__ opw, char* __restrict__ wsb) {
  float* cb = (float*)(wsb + OFF_CB);
  int t = blockIdx.x * 256 + threadIdx.x;
  int i = t >> 7, o = t & 127;
  const float* op = opw + i * 16384 + o * 128;
  const float* ib = ipb + i * 384 + 256;
  float s = opb[i * 128 + o];
#pragma unroll 4
  for (int m = 0; m < 128; ++m) s = fmaf(op[m], ib[m], s);
  cb[t] = s;
}

// writes hi/lo bf16 pack AND f32 pack
__global__ void k_mt(const float* __restrict__ tm_w, char* __restrict__ wsb) {
  const float* cw = (const float*)(wsb + OFF_CW);
  unsigned short* dh = (unsigned short*)(wsb + OFF_MTH);
  unsigned short* dl = (unsigned short*)(wsb + OFF_MTL);
  float* d4 = (float*)(wsb + OFF_MT4);
  int n = blockIdx.x * 256 + threadIdx.x;  // 768*256
  int k = n >> 8, c = n & 255;
  const float* p = cw + ((c >> 7) ? 3 : 0) * 16384 + (c & 127);
  float s = 0.f;
#pragma unroll 4
  for (int d = 0; d < 128; ++d) s = fmaf(p[d * 128], tm_w[d * 768 + k], s);
  unsigned short h, l;
  split2(s, h, l);
  int ofs = (((k >> 3) * 256 + c) << 3) + (k & 7);
  dh[ofs] = h;
  dl[ofs] = l;
  d4[(((k >> 2) * 256 + c) << 2) + (k & 3)] = s;
}

__global__ void k_mu(const float* __restrict__ um_w, char* __restrict__ wsb) {
  const float* cw = (const float*)(wsb + OFF_CW);
  unsigned short* dh = (unsigned short*)(wsb + OFF_MUH);
  unsigned short* dl = (unsigned short*)(wsb + OFF_MUL);
  float* d4 = (float*)(wsb + OFF_MU4);
  int n = blockIdx.x * 256 + threadIdx.x;  // 256*256
  int k = n >> 8, c = n & 255;
  const float* p = cw + ((c >> 7) ? 1 : 2) * 16384 + (c & 127);
  float s = 0.f;
#pragma unroll 4
  for (int d = 0; d < 128; ++d) s = fmaf(p[d * 128], um_w[d * 256 + k], s);
  unsigned short h, l;
  split2(s, h, l);
  int ofs = (((k >> 3) * 256 + c) << 3) + (k & 7);
  dh[ofs] = h;
  dl[ofs] = l;
  d4[(((k >> 2) * 256 + c) << 2) + (k & 3)] = s;
}

__global__ void k_bias_tu(const float* __restrict__ tm_b, const float* __restrict__ um_b,
                          char* __restrict__ wsb) {
  const float* cw = (const float*)(wsb + OFF_CW);
  const float* cb = (const float*)(wsb + OFF_CB);
  float* bT = (float*)(wsb + OFF_BT);
  float* bU = (float*)(wsb + OFF_BU);
  int t = blockIdx.x * 256 + threadIdx.x;
  if (t < 256) {
    int sel = (t >> 7) ? 3 : 0;
    const float* p = cw + sel * 16384 + (t & 127);
    float s = cb[sel * 128 + (t & 127)];
#pragma unroll 4
    for (int d = 0; d < 128; ++d) s = fmaf(p[d * 128], tm_b[d], s);
    bT[t] = s;
  } else {
    int c = t - 256;
    int sel = (c >> 7) ? 1 : 2;
    const float* p = cw + sel * 16384 + (c & 127);
    float s = cb[sel * 128 + (c & 127)];
#pragma unroll 4
    for (int d = 0; d < 128; ++d) s = fmaf(p[d * 128], um_b[d], s);
    bU[c] = s;
  }
}

__global__ void k_pack_gw4(const float* __restrict__ tg_w, const float* __restrict__ ug_w,
                           char* __restrict__ wsb) {
  float* dst = (float*)(wsb + OFF_GW4);
  int idx = blockIdx.x * 256 + threadIdx.x;
  int j = idx >> 8, n = idx & 255;
  float v = (n < 128) ? tg_w[n * 256 + j] : ug_w[(n - 128) * 256 + j];
  dst[(((j >> 2) * 256 + n) << 2) + (j & 3)] = v;
}

__global__ void k_pack_fw4(const float* __restrict__ ff_w, char* __restrict__ wsb) {
  float* dst = (float*)(wsb + OFF_FW4);
  int idx = blockIdx.x * 256 + threadIdx.x;
  int j = idx >> 8, n = idx & 255;
  dst[(((j >> 2) * 256 + n) << 2) + (j & 3)] = ff_w[n * 256 + j];
}

// ---------------- fused main (self-checking) ----------------

#define SWZ(byte, row) ((byte) ^ (((row) & 7) << 4))

__launch_bounds__(512)
__global__ void k_main(const float* __restrict__ xt_g, const float* __restrict__ xu_g,
                       const char* __restrict__ wsb,
                       const float* __restrict__ tg_b, const float* __restrict__ ug_b,
                       const float* __restrict__ ff_b, const float* __restrict__ ln_g,
                       const float* __restrict__ ln_b, float* __restrict__ out) {
  __shared__ __align__(16) char sm[65536];
  constexpr int XTL = 24576, XUH = 49152, XUL = 57344;
  constexpr int SP = 516;
  constexpr int FP = 260;
  float* S = (float*)sm;
  float* F = (float*)(sm + 48896);
  float* H = (float*)sm;

  const int t = threadIdx.x;
  const int wave = t >> 6, lane = t & 63;
  const int lrow = lane & 15;
  const int lk8 = lane >> 4;
  const int n0w = wave * 32;
  const long row0 = (long)blockIdx.x * 16;

  const float* bT = (const float*)(wsb + OFF_BT);
  const float* bU = (const float*)(wsb + OFF_BU);

  // ---- staging hi/lo (round-9 verbatim) ----
  {
    const float4* gx = (const float4*)(xt_g + row0 * 768);
#pragma unroll
    for (int it = 0; it < 6; ++it) {
      int idx = it * 512 + t;
      float4 v = gx[idx];
      int row = idx / 192, rem = idx - row * 192;
      int b0 = row * 1536 + rem * 8;
      ushort4 hh, ll;
      split2(v.x, hh.x, ll.x); split2(v.y, hh.y, ll.y);
      split2(v.z, hh.z, ll.z); split2(v.w, hh.w, ll.w);
      *(ushort4*)(sm + SWZ(b0, row)) = hh;
      *(ushort4*)(sm + XTL + SWZ(b0, row)) = ll;
    }
    const float4* gu = (const float4*)(xu_g + row0 * 256);
#pragma unroll
    for (int it = 0; it < 2; ++it) {
      int idx = it * 512 + t;
      float4 v = gu[idx];
      int row = idx >> 6, rem = idx & 63;
      int b0 = row * 512 + rem * 8;
      ushort4 hh, ll;
      split2(v.x, hh.x, ll.x); split2(v.y, hh.y, ll.y);
      split2(v.z, hh.z, ll.z); split2(v.w, hh.w, ll.w);
      *(ushort4*)(sm + XUH + SWZ(b0, row)) = hh;
      *(ushort4*)(sm + XUL + SWZ(b0, row)) = ll;
    }
  }
  __syncthreads();

  floatx4 zero = {0.f, 0.f, 0.f, 0.f};

  // ---- MFMA stage 1 (round-9 verbatim) ----
  floatx4 acc1[2] = {zero, zero};
  {
    const char* wh = wsb + OFF_MTH;
    const char* wl = wsb + OFF_MTL;
#pragma unroll 4
    for (int k0 = 0; k0 < 768; k0 += 32) {
      int kb = (k0 + lk8 * 8) * 2;
      short8v ah = *(const short8v*)(sm + SWZ(lrow * 1536 + kb, lrow));
      short8v al = *(const short8v*)(sm + XTL + SWZ(lrow * 1536 + kb, lrow));
      int k8 = (k0 >> 3) + lk8;
      int o0 = (k8 * 256 + n0w + lrow) << 4;
      int o1 = (k8 * 256 + n0w + 16 + lrow) << 4;
      short8v bh0 = *(const short8v*)(wh + o0);
      short8v bh1 = *(const short8v*)(wh + o1);
      short8v bl0 = *(const short8v*)(wl + o0);
      short8v bl1 = *(const short8v*)(wl + o1);
      acc1[0] = __builtin_amdgcn_mfma_f32_16x16x32_bf16(ah, bh0, acc1[0], 0, 0, 0);
      acc1[0] = __builtin_amdgcn_mfma_f32_16x16x32_bf16(ah, bl0, acc1[0], 0, 0, 0);
      acc1[0] = __builtin_amdgcn_mfma_f32_16x16x32_bf16(al, bh0, acc1[0], 0, 0, 0);
      acc1[1] = __builtin_amdgcn_mfma_f32_16x16x32_bf16(ah, bh1, acc1[1], 0, 0, 0);
      acc1[1] = __builtin_amdgcn_mfma_f32_16x16x32_bf16(ah, bl1, acc1[1], 0, 0, 0);
      acc1[1] = __builtin_amdgcn_mfma_f32_16x16x32_bf16(al, bh1, acc1[1], 0, 0, 0);
    }
  }

  // ---- MFMA stage 2 (round-9 verbatim) ----
  floatx4 acc2[2] = {zero, zero};
  {
    const char* wh = wsb + OFF_MUH;
    const char* wl = wsb + OFF_MUL;
#pragma unroll
    for (int k0 = 0; k0 < 256; k0 += 32) {
      int kb = (k0 + lk8 * 8) * 2;
      short8v ah = *(const short8v*)(sm + XUH + SWZ(lrow * 512 + kb, lrow));
      short8v al = *(const short8v*)(sm + XUL + SWZ(lrow * 512 + kb, lrow));
      int k8 = (k0 >> 3) + lk8;
      int o0 = (k8 * 256 + n0w + lrow) << 4;
      int o1 = (k8 * 256 + n0w + 16 + lrow) << 4;
      short8v bh0 = *(const short8v*)(wh + o0);
      short8v bh1 = *(const short8v*)(wh + o1);
      short8v bl0 = *(const short8v*)(wl + o0);
      short8v bl1 = *(const short8v*)(wl + o1);
      acc2[0] = __builtin_amdgcn_mfma_f32_16x16x32_bf16(ah, bh0, acc2[0], 0, 0, 0);
      acc2[0] = __builtin_amdgcn_mfma_f32_16x16x32_bf16(ah, bl0, acc2[0], 0, 0, 0);
      acc2[0] = __builtin_amdgcn_mfma_f32_16x16x32_bf16(al, bh0, acc2[0], 0, 0, 0);
      acc2[1] = __builtin_amdgcn_mfma_f32_16x16x32_bf16(ah, bh1, acc2[1], 0, 0, 0);
      acc2[1] = __builtin_amdgcn_mfma_f32_16x16x32_bf16(ah, bl1, acc2[1], 0, 0, 0);
      acc2[1] = __builtin_amdgcn_mfma_f32_16x16x32_bf16(al, bh1, acc2[1], 0, 0, 0);
    }
  }
  __syncthreads();  // staged x dead; region becomes S

  // ---- INDEPENDENT scalar-f32 S (reference; drives the real output) ----
  // thread map: rq = t>>7 (row group), c0 = (t&127)*2 (col pair)
  const int rq = t >> 7, c0 = (t & 127) * 2;
  {
    const float4* MT4 = (const float4*)(wsb + OFF_MT4);
    const float4* MU4 = (const float4*)(wsb + OFF_MU4);
    const float4* xr0 = (const float4*)(xt_g + (row0 + rq * 4 + 0) * 768);
    const float4* xr1 = (const float4*)(xt_g + (row0 + rq * 4 + 1) * 768);
    const float4* xr2 = (const float4*)(xt_g + (row0 + rq * 4 + 2) * 768);
    const float4* xr3 = (const float4*)(xt_g + (row0 + rq * 4 + 3) * 768);
    float a[4][2] = {};
    for (int k4 = 0; k4 < 192; ++k4) {
      float4 w0 = MT4[k4 * 256 + c0];
      float4 w1 = MT4[k4 * 256 + c0 + 1];
      float4 x0 = xr0[k4], x1 = xr1[k4], x2 = xr2[k4], x3 = xr3[k4];
      a[0][0] += x0.x * w0.x + x0.y * w0.y + x0.z * w0.z + x0.w * w0.w;
      a[0][1] += x0.x * w1.x + x0.y * w1.y + x0.z * w1.z + x0.w * w1.w;
      a[1][0] += x1.x * w0.x + x1.y * w0.y + x1.z * w0.z + x1.w * w0.w;
      a[1][1] += x1.x * w1.x + x1.y * w1.y + x1.z * w1.z + x1.w * w1.w;
      a[2][0] += x2.x * w0.x + x2.y * w0.y + x2.z * w0.z + x2.w * w0.w;
      a[2][1] += x2.x * w1.x + x2.y * w1.y + x2.z * w1.z + x2.w * w1.w;
      a[3][0] += x3.x * w0.x + x3.y * w0.y + x3.z * w0.z + x3.w * w0.w;
      a[3][1] += x3.x * w1.x + x3.y * w1.y + x3.z * w1.z + x3.w * w1.w;
    }
    const float4* ur0 = (const float4*)(xu_g + (row0 + rq * 4 + 0) * 256);
    const float4* ur1 = (const float4*)(xu_g + (row0 + rq * 4 + 1) * 256);
    const float4* ur2 = (const float4*)(xu_g + (row0 + rq * 4 + 2) * 256);
    const float4* ur3 = (const float4*)(xu_g + (row0 + rq * 4 + 3) * 256);
    float b[4][2] = {};
    for (int k4 = 0; k4 < 64; ++k4) {
      float4 w0 = MU4[k4 * 256 + c0];
      float4 w1 = MU4[k4 * 256 + c0 + 1];
      float4 x0 = ur0[k4], x1 = ur1[k4], x2 = ur2[k4], x3 = ur3[k4];
      b[0][0] += x0.x * w0.x + x0.y * w0.y + x0.z * w0.z + x0.w * w0.w;
      b[0][1] += x0.x * w1.x + x0.y * w1.y + x0.z * w1.z + x0.w * w1.w;
      b[1][0] += x1.x * w0.x + x1.y * w0.y + x1.z * w0.z + x1.w * w0.w;
      b[1][1] += x1.x * w1.x + x1.y * w1.y + x1.z * w1.z + x1.w * w1.w;
      b[2][0] += x2.x * w0.x + x2.y * w0.y + x2.z * w0.z + x2.w * w0.w;
      b[2][1] += x2.x * w1.x + x2.y * w1.y + x2.z * w1.z + x2.w * w1.w;
      b[3][0] += x3.x * w0.x + x3.y * w0.y + x3.z * w0.z + x3.w * w0.w;
      b[3][1] += x3.x * w1.x + x3.y * w1.y + x3.z * w1.z + x3.w * w1.w;
    }
    int sT0 = (c0 < 128) ? c0 : 256 + c0;
    float bt0 = bT[c0], bt1 = bT[c0 + 1], bu0 = bU[c0], bu1 = bU[c0 + 1];
#pragma unroll
    for (int r = 0; r < 4; ++r) {
      int row = rq * 4 + r;
      S[row * SP + sT0]         = a[r][0] + bt0;
      S[row * SP + sT0 + 1]     = a[r][1] + bt1;
      S[row * SP + 128 + c0]    = b[r][0] + bu0;
      S[row * SP + 128 + c0 + 1] = b[r][1] + bu1;
    }
  }
  __syncthreads();

  // ---- COMPARE: MFMA acc vs scalar S ----
  bool bad = false;
  float P = 0.f;
#pragma unroll
  for (int nt = 0; nt < 2; ++nt) {
    int n = n0w + nt * 16 + lrow;
    int sT = (n < 128) ? n : 256 + n;
    float bvT = bT[n], bvU = bU[n];
#pragma unroll
    for (int reg = 0; reg < 4; ++reg) {
      int grow = lk8 * 4 + reg;
      float refT = S[grow * SP + sT];
      float dT = (acc1[nt][reg] + bvT) - refT;
      if (!(fabsf(dT) <= 0.01f + 0.05f * fabsf(refT))) {
        bad = true;
        P = fmaxf(P, 10000.f + 1000.f * lk8 + 100.f * reg + 10.f * nt + 0.1f * lrow);
      }
      float refU = S[grow * SP + 128 + n];
      float dU = (acc2[nt][reg] + bvU) - refU;
      if (!(fabsf(dU) <= 0.01f + 0.05f * fabsf(refU))) {
        bad = true;
        P = fmaxf(P, 20000.f + 1000.f * lk8 + 100.f * reg + 10.f * nt + 0.1f * lrow);
      }
    }
  }

  // ---- stage 3 + mix (round-9 verbatim, scalar S) ----
  {
    const int so3 = (c0 < 128) ? 0 : 256;
    const float4* GW = (const float4*)(wsb + OFF_GW4);
    float acc[4][2] = {};
    for (int j = 0; j < 256; j += 4) {
      float4 w0 = GW[(j >> 2) * 256 + c0];
      float4 w1 = GW[(j >> 2) * 256 + c0 + 1];
#pragma unroll
      for (int r = 0; r < 4; ++r) {
        const float4 sv = *(const float4*)&S[(rq * 4 + r) * SP + so3 + j];
        acc[r][0] = fmaf(sv.x, w0.x, fmaf(sv.y, w0.y, fmaf(sv.z, w0.z, fmaf(sv.w, w0.w, acc[r][0]))));
        acc[r][1] = fmaf(sv.x, w1.x, fmaf(sv.y, w1.y, fmaf(sv.z, w1.z, fmaf(sv.w, w1.w, acc[r][1]))));
      }
    }
    float gb0 = (c0 < 128) ? tg_b[c0] : ug_b[c0 - 128];
    float gb1 = (c0 < 128) ? tg_b[c0 + 1] : ug_b[c0 - 127];
    int am = (c0 < 128) ? c0 : 128 + c0;
#pragma unroll
    for (int r = 0; r < 4; ++r) {
      int row = rq * 4 + r;
      float g0 = 1.f / (1.f + __expf(-(acc[r][0] + gb0)));
      float g1 = 1.f / (1.f + __expf(-(acc[r][1] + gb1)));
      float a0 = S[row * SP + am],     b0v = S[row * SP + am + 128];
      float a1 = S[row * SP + am + 1], b1v = S[row * SP + am + 129];
      F[row * FP + c0]     = fmaf(g0, b0v - a0, a0);
      F[row * FP + c0 + 1] = fmaf(g1, b1v - a1, a1);
    }
  }
  __syncthreads();

  // ---- stage 4 (round-9 verbatim) ----
  {
    const float4* FW = (const float4*)(wsb + OFF_FW4);
    float acc[4][2] = {};
    for (int j = 0; j < 256; j += 4) {
      float4 w0 = FW[(j >> 2) * 256 + c0];
      float4 w1 = FW[(j >> 2) * 256 + c0 + 1];
#pragma unroll
      for (int r = 0; r < 4; ++r) {
        const float4 fv = *(const float4*)&F[(rq * 4 + r) * FP + j];
        acc[r][0] = fmaf(fv.x, w0.x, fmaf(fv.y, w0.y, fmaf(fv.z, w0.z, fmaf(fv.w, w0.w, acc[r][0]))));
        acc[r][1] = fmaf(fv.x, w1.x, fmaf(fv.y, w1.y, fmaf(fv.z, w1.z, fmaf(fv.w, w1.w, acc[r][1]))));
      }
    }
    float fb0 = ff_b[c0], fb1 = ff_b[c0 + 1];
#pragma unroll
    for (int r = 0; r < 4; ++r) {
      int row = rq * 4 + r;
      H[row * FP + c0]     = acc[r][0] + fb0;
      H[row * FP + c0 + 1] = acc[r][1] + fb1;
    }
  }
  __syncthreads();

  // ---- LayerNorm + ReLU + store (round-9 verbatim) ----
  {
    int r = t >> 5, q = t & 31;
    const float* Hr = H + r * FP + q * 8;
    float4 hv0 = *(const float4*)Hr;
    float4 hv1 = *(const float4*)(Hr + 4);
    float s1 = hv0.x + hv0.y + hv0.z + hv0.w + hv1.x + hv1.y + hv1.z + hv1.w;
    float s2 = hv0.x * hv0.x + hv0.y * hv0.y + hv0.z * hv0.z + hv0.w * hv0.w +
               hv1.x * hv1.x + hv1.y * hv1.y + hv1.z * hv1.z + hv1.w * hv1.w;
#pragma unroll
    for (int off = 1; off < 32; off <<= 1) {
      s1 += __shfl_xor(s1, off);
      s2 += __shfl_xor(s2, off);
    }
    float mu = s1 * (1.f / 256.f);
    float var = s2 * (1.f / 256.f) - mu * mu;
    float rstd = rsqrtf(var + 1e-5f);
    float* op = out + (row0 + r) * 256 + q * 8;
    float4 gv0 = *(const float4*)(ln_g + q * 8);
    float4 gv1 = *(const float4*)(ln_g + q * 8 + 4);
    float4 bv0 = *(const float4*)(ln_b + q * 8);
    float4 bv1 = *(const float4*)(ln_b + q * 8 + 4);
    float4 o0, o1;
    o0.x = fmaf((hv0.x - mu) * rstd, gv0.x, bv0.x);
    o0.y = fmaf((hv0.y - mu) * rstd, gv0.y, bv0.y);
    o0.z = fmaf((hv0.z - mu) * rstd, gv0.z, bv0.z);
    o0.w = fmaf((hv0.w - mu) * rstd, gv0.w, bv0.w);
    o1.x = fmaf((hv1.x - mu) * rstd, gv1.x, bv1.x);
    o1.y = fmaf((hv1.y - mu) * rstd, gv1.y, bv1.y);
    o1.z = fmaf((hv1.z - mu) * rstd, gv1.z, bv1.z);
    o1.w = fmaf((hv1.w - mu) * rstd, gv1.w, bv1.w);
    o0.x = o0.x > 0.f ? o0.x : 0.f;  o0.y = o0.y > 0.f ? o0.y : 0.f;
    o0.z = o0.z > 0.f ? o0.z : 0.f;  o0.w = o0.w > 0.f ? o0.w : 0.f;
    o1.x = o1.x > 0.f ? o1.x : 0.f;  o1.y = o1.y > 0.f ? o1.y : 0.f;
    o1.z = o1.z > 0.f ? o1.z : 0.f;  o1.w = o1.w > 0.f ? o1.w : 0.f;
    *(float4*)op = o0;
    *(float4*)(op + 4) = o1;
  }

  // ---- poison: encode mismatch coordinates into out ----
  if (bad) out[row0 * 256 + t] = P;
}

}  // namespace

extern "C" void kernel_launch(void* const* d_in, const int* in_sizes, int n_in,
                              void* d_out, int out_size, void* d_ws, size_t ws_size,
                              hipStream_t stream) {
  const float* text = (const float*)d_in[0];
  const float* user = (const float*)d_in[1];
  const float* tm_w = (const float*)d_in[2];
  const float* tm_b = (const float*)d_in[3];
  const float* um_w = (const float*)d_in[4];
  const float* um_b = (const float*)d_in[5];
  const float* ipw = (const float*)d_in[6];
  const float* ipb = (const float*)d_in[7];
  const float* opw = (const float*)d_in[8];
  const float* opb = (const float*)d_in[9];
  const float* tg_w = (const float*)d_in[10];
  const float* tg_b = (const float*)d_in[11];
  const float* ug_w = (const float*)d_in[12];
  const float* ug_b = (const float*)d_in[13];
  const float* ff_w = (const float*)d_in[14];
  const float* ff_b = (const float*)d_in[15];
  const float* ln_g = (const float*)d_in[16];
  const float* ln_b = (const float*)d_in[17];
  char* wsb = (char*)d_ws;
  float* out = (float*)d_out;

  k_combine<<<256, 256, 0, stream>>>(ipw, opw, wsb);
  k_combine_bias<<<2, 256, 0, stream>>>(ipb, opb, opw, wsb);
  k_mt<<<768, 256, 0, stream>>>(tm_w, wsb);
  k_mu<<<256, 256, 0, stream>>>(um_w, wsb);
  k_bias_tu<<<2, 256, 0, stream>>>(tm_b, um_b, wsb);
  k_pack_gw4<<<256, 256, 0, stream>>>(tg_w, ug_w, wsb);
  k_pack_fw4<<<256, 256, 0, stream>>>(ff_w, wsb);

  k_main<<<4096, 512, 0, stream>>>(text, user, wsb, tg_b, ug_b, ff_b, ln_g, ln_b, out);
}

// Round 13
// 646.619 us; speedup vs baseline: 3.4429x; 3.4429x over previous
//
#include <hip/hip_runtime.h>
#include <hip/hip_bf16.h>

// MultiViewFusion — two-kernel split (validated pieces only).
// Evidence ledger:
//   R5  PASS 0.0156: scalar-f32 fused (folding algebra correct).
//   R6-R9 FAIL 0.13-0.17: any kernel where MFMA acc is scattered into LDS and
//        re-read (invariant under datapath precision and S dtype).
//   R10 PASS 0.0156 + ZERO self-check poisons: MFMA stages 1/2 (hi/lo staging,
//        swizzle, fragments) match scalar-f32 reference at every coordinate;
//        scalar second half correct.
// => The ONLY unexonerated op is acc->LDS->read. This round eliminates it:
//    kA: MFMA stages 1/2 -> f32 S to GLOBAL ws (m97-style acc->VALU->store).
//    kB: R5-verbatim phases 3/4/5 with S staged from global.
// Host falls back to the complete R5 fused kernel if ws_size < ~137.2 MB.
// (Round 13 = identical source; rounds 11 and 12 both died on container infra
// before executing anything — same dead pod as rounds 2-4.)

namespace {

typedef __attribute__((ext_vector_type(8))) short short8v;   // 8 bf16 = 4 VGPR
typedef __attribute__((ext_vector_type(4))) float floatx4;   // MFMA C/D

// workspace byte offsets
constexpr int OFF_CW  = 0;        // f32 CWt[4][128][128]
constexpr int OFF_CB  = 262144;   // f32 cv[4][128]
constexpr int OFF_BT  = 264192;   // f32 bT[256]  [ts|uc]
constexpr int OFF_BU  = 265216;   // f32 bU[256]  [tc|us]
constexpr int OFF_MTH = 266240;   // bf16 M_text hi packed [96][256][8]
constexpr int OFF_MTL = 659456;   // bf16 M_text lo
constexpr int OFF_MUH = 1052672;  // bf16 M_user hi packed [32][256][8]
constexpr int OFF_MUL = 1183744;  // bf16 M_user lo
constexpr int OFF_TG4 = 1314816;  // f32 tg_w pack [64][128][4]
constexpr int OFF_UG4 = 1445888;  // f32 ug_w pack [64][128][4]
constexpr int OFF_FF4 = 1576960;  // f32 ff_w pack [64][256][4]
constexpr int OFF_MT4 = 1839104;  // f32 M_text pack [192][256][4]  (fallback)
constexpr int OFF_MU4 = 2625536;  // f32 M_user pack [64][256][4]   (fallback)
constexpr long OFF_S  = 2887680;  // f32 S [65536][512] = 134217728 B (fast path)
constexpr long WS_NEED = OFF_S + 134217728L;

__device__ inline unsigned short f2b(float f) {
  __hip_bfloat16 h = __float2bfloat16(f);
  return __builtin_bit_cast(unsigned short, h);
}
__device__ inline float b2f(unsigned short u) {
  unsigned int v = ((unsigned int)u) << 16;
  return __builtin_bit_cast(float, v);
}
__device__ inline void split2(float v, unsigned short& h, unsigned short& l) {
  h = f2b(v);
  l = f2b(v - b2f(h));
}

// ---------------- precompute (tiny, L2-resident; R5/R8-validated) ----------------

__global__ void k_combine(const float* __restrict__ ipw, const float* __restrict__ opw,
                          char* __restrict__ wsb) {
  float* cw = (float*)(wsb + OFF_CW);
  int n = blockIdx.x * 256 + threadIdx.x;
  int i = n >> 14, o = (n >> 7) & 127, d = n & 127;
  const float* op = opw + i * 16384 + o * 128;
  const float* iv = ipw + i * 49152 + 256 * 128 + d;
  float s = 0.f;
#pragma unroll 4
  for (int m = 0; m < 128; ++m) s = fmaf(op[m], iv[m * 128], s);
  cw[i * 16384 + d * 128 + o] = s;
}

__global__ void k_combine_bias(const float* __restrict__ ipb, const float* __restrict__ opb,
                               const float* __restrict__ opw, char* __restrict__ wsb) {
  float* cb = (float*)(wsb + OFF_CB);
  int t = blockIdx.x * 256 + threadIdx.x;
  int i = t >> 7, o = t & 127;
  const float* op = opw + i * 16384 + o * 128;
  const float* ib = ipb + i * 384 + 256;
  float s = opb[i * 128 + o];
#pragma unroll 4
  for (int m = 0; m < 128; ++m) s = fmaf(op[m], ib[m], s);
  cb[t] = s;
}

// hi/lo bf16 pack for MFMA (fast path)
__global__ void k_mt_hl(const float* __restrict__ tm_w, char* __restrict__ wsb) {
  const float* cw = (const float*)(wsb + OFF_CW);
  unsigned short* dh = (unsigned short*)(wsb + OFF_MTH);
  unsigned short* dl = (unsigned short*)(wsb + OFF_MTL);
  int n = blockIdx.x * 256 + threadIdx.x;  // 768*256
  int k = n >> 8, c = n & 255;
  const float* p = cw + ((c >> 7) ? 3 : 0) * 16384 + (c & 127);
  float s = 0.f;
#pragma unroll 4
  for (int d = 0; d < 128; ++d) s = fmaf(p[d * 128], tm_w[d * 768 + k], s);
  unsigned short h, l;
  split2(s, h, l);
  int ofs = (((k >> 3) * 256 + c) << 3) + (k & 7);
  dh[ofs] = h;
  dl[ofs] = l;
}

__global__ void k_mu_hl(const float* __restrict__ um_w, char* __restrict__ wsb) {
  const float* cw = (const float*)(wsb + OFF_CW);
  unsigned short* dh = (unsigned short*)(wsb + OFF_MUH);
  unsigned short* dl = (unsigned short*)(wsb + OFF_MUL);
  int n = blockIdx.x * 256 + threadIdx.x;  // 256*256
  int k = n >> 8, c = n & 255;
  const float* p = cw + ((c >> 7) ? 1 : 2) * 16384 + (c & 127);
  float s = 0.f;
#pragma unroll 4
  for (int d = 0; d < 128; ++d) s = fmaf(p[d * 128], um_w[d * 256 + k], s);
  unsigned short h, l;
  split2(s, h, l);
  int ofs = (((k >> 3) * 256 + c) << 3) + (k & 7);
  dh[ofs] = h;
  dl[ofs] = l;
}

// f32 [K/4][256][4] packs (fallback scalar path; R5 verbatim)
__global__ void k_mt4(const float* __restrict__ tm_w, char* __restrict__ wsb) {
  const float* cw = (const float*)(wsb + OFF_CW);
  float* dst = (float*)(wsb + OFF_MT4);
  int n = blockIdx.x * 256 + threadIdx.x;  // 768*256
  int k = n >> 8, c = n & 255;
  const float* p = cw + ((c >> 7) ? 3 : 0) * 16384 + (c & 127);
  float s = 0.f;
#pragma unroll 4
  for (int d = 0; d < 128; ++d) s = fmaf(p[d * 128], tm_w[d * 768 + k], s);
  dst[(((k >> 2) * 256 + c) << 2) + (k & 3)] = s;
}

__global__ void k_mu4(const float* __restrict__ um_w, char* __restrict__ wsb) {
  const float* cw = (const float*)(wsb + OFF_CW);
  float* dst = (float*)(wsb + OFF_MU4);
  int n = blockIdx.x * 256 + threadIdx.x;  // 256*256
  int k = n >> 8, c = n & 255;
  const float* p = cw + ((c >> 7) ? 1 : 2) * 16384 + (c & 127);
  float s = 0.f;
#pragma unroll 4
  for (int d = 0; d < 128; ++d) s = fmaf(p[d * 128], um_w[d * 256 + k], s);
  dst[(((k >> 2) * 256 + c) << 2) + (k & 3)] = s;
}

__global__ void k_bias_tu(const float* __restrict__ tm_b, const float* __restrict__ um_b,
                          char* __restrict__ wsb) {
  const float* cw = (const float*)(wsb + OFF_CW);
  const float* cb = (const float*)(wsb + OFF_CB);
  float* bT = (float*)(wsb + OFF_BT);
  float* bU = (float*)(wsb + OFF_BU);
  int t = blockIdx.x * 256 + threadIdx.x;
  if (t < 256) {
    int sel = (t >> 7) ? 3 : 0;
    const float* p = cw + sel * 16384 + (t & 127);
    float s = cb[sel * 128 + (t & 127)];
#pragma unroll 4
    for (int d = 0; d < 128; ++d) s = fmaf(p[d * 128], tm_b[d], s);
    bT[t] = s;
  } else {
    int c = t - 256;
    int sel = (c >> 7) ? 1 : 2;
    const float* p = cw + sel * 16384 + (c & 127);
    float s = cb[sel * 128 + (c & 127)];
#pragma unroll 4
    for (int d = 0; d < 128; ++d) s = fmaf(p[d * 128], um_b[d], s);
    bU[c] = s;
  }
}

// dst[((k>>2)*R + o)*4 + (k&3)] = src[o*C + k]  (R5 verbatim)
__global__ void k_transpose4(const float* __restrict__ src, float* __restrict__ dst,
                             int R, int C) {
  int n = blockIdx.x * 256 + threadIdx.x;
  if (n >= R * C) return;
  int o = n / C, k = n % C;
  dst[(((k >> 2) * R + o) << 2) + (k & 3)] = src[n];
}

// ---------------- kA: MFMA stages 1/2 -> global S (fast path) ----------------
// 512 threads = 8 waves, 16 rows/block, 64 KB LDS (R9-verbatim front).

#define SWZ(byte, row) ((byte) ^ (((row) & 7) << 4))

__launch_bounds__(512)
__global__ void k_s12(const float* __restrict__ xt_g, const float* __restrict__ xu_g,
                      const char* __restrict__ wsb, float* __restrict__ Sg) {
  __shared__ __align__(16) char sm[65536];
  constexpr int XTL = 24576, XUH = 49152, XUL = 57344;

  const int t = threadIdx.x;
  const int wave = t >> 6, lane = t & 63;
  const int lrow = lane & 15;
  const int lk8 = lane >> 4;
  const int n0w = wave * 32;
  const long row0 = (long)blockIdx.x * 16;

  const float* bT = (const float*)(wsb + OFF_BT);
  const float* bU = (const float*)(wsb + OFF_BU);

  // ---- staging hi/lo (R9/R10-verbatim, validated by R10 compare) ----
  {
    const float4* gx = (const float4*)(xt_g + row0 * 768);
#pragma unroll
    for (int it = 0; it < 6; ++it) {
      int idx = it * 512 + t;
      float4 v = gx[idx];
      int row = idx / 192, rem = idx - row * 192;
      int b0 = row * 1536 + rem * 8;
      ushort4 hh, ll;
      split2(v.x, hh.x, ll.x); split2(v.y, hh.y, ll.y);
      split2(v.z, hh.z, ll.z); split2(v.w, hh.w, ll.w);
      *(ushort4*)(sm + SWZ(b0, row)) = hh;
      *(ushort4*)(sm + XTL + SWZ(b0, row)) = ll;
    }
    const float4* gu = (const float4*)(xu_g + row0 * 256);
#pragma unroll
    for (int it = 0; it < 2; ++it) {
      int idx = it * 512 + t;
      float4 v = gu[idx];
      int row = idx >> 6, rem = idx & 63;
      int b0 = row * 512 + rem * 8;
      ushort4 hh, ll;
      split2(v.x, hh.x, ll.x); split2(v.y, hh.y, ll.y);
      split2(v.z, hh.z, ll.z); split2(v.w, hh.w, ll.w);
      *(ushort4*)(sm + XUH + SWZ(b0, row)) = hh;
      *(ushort4*)(sm + XUL + SWZ(b0, row)) = ll;
    }
  }
  __syncthreads();

  floatx4 zero = {0.f, 0.f, 0.f, 0.f};

  // ---- stage 1: text GEMM K=768, 3-term hi/lo split (R10-validated) ----
  floatx4 acc1[2] = {zero, zero};
  {
    const char* wh = wsb + OFF_MTH;
    const char* wl = wsb + OFF_MTL;
#pragma unroll 4
    for (int k0 = 0; k0 < 768; k0 += 32) {
      int kb = (k0 + lk8 * 8) * 2;
      short8v ah = *(const short8v*)(sm + SWZ(lrow * 1536 + kb, lrow));
      short8v al = *(const short8v*)(sm + XTL + SWZ(lrow * 1536 + kb, lrow));
      int k8 = (k0 >> 3) + lk8;
      int o0 = (k8 * 256 + n0w + lrow) << 4;
      int o1 = (k8 * 256 + n0w + 16 + lrow) << 4;
      short8v bh0 = *(const short8v*)(wh + o0);
      short8v bh1 = *(const short8v*)(wh + o1);
      short8v bl0 = *(const short8v*)(wl + o0);
      short8v bl1 = *(const short8v*)(wl + o1);
      acc1[0] = __builtin_amdgcn_mfma_f32_16x16x32_bf16(ah, bh0, acc1[0], 0, 0, 0);
      acc1[0] = __builtin_amdgcn_mfma_f32_16x16x32_bf16(ah, bl0, acc1[0], 0, 0, 0);
      acc1[0] = __builtin_amdgcn_mfma_f32_16x16x32_bf16(al, bh0, acc1[0], 0, 0, 0);
      acc1[1] = __builtin_amdgcn_mfma_f32_16x16x32_bf16(ah, bh1, acc1[1], 0, 0, 0);
      acc1[1] = __builtin_amdgcn_mfma_f32_16x16x32_bf16(ah, bl1, acc1[1], 0, 0, 0);
      acc1[1] = __builtin_amdgcn_mfma_f32_16x16x32_bf16(al, bh1, acc1[1], 0, 0, 0);
    }
  }

  // ---- stage 2: user GEMM K=256 (R10-validated) ----
  floatx4 acc2[2] = {zero, zero};
  {
    const char* wh = wsb + OFF_MUH;
    const char* wl = wsb + OFF_MUL;
#pragma unroll
    for (int k0 = 0; k0 < 256; k0 += 32) {
      int kb = (k0 + lk8 * 8) * 2;
      short8v ah = *(const short8v*)(sm + XUH + SWZ(lrow * 512 + kb, lrow));
      short8v al = *(const short8v*)(sm + XUL + SWZ(lrow * 512 + kb, lrow));
      int k8 = (k0 >> 3) + lk8;
      int o0 = (k8 * 256 + n0w + lrow) << 4;
      int o1 = (k8 * 256 + n0w + 16 + lrow) << 4;
      short8v bh0 = *(const short8v*)(wh + o0);
      short8v bh1 = *(const short8v*)(wh + o1);
      short8v bl0 = *(const short8v*)(wl + o0);
      short8v bl1 = *(const short8v*)(wl + o1);
      acc2[0] = __builtin_amdgcn_mfma_f32_16x16x32_bf16(ah, bh0, acc2[0], 0, 0, 0);
      acc2[0] = __builtin_amdgcn_mfma_f32_16x16x32_bf16(ah, bl0, acc2[0], 0, 0, 0);
      acc2[0] = __builtin_amdgcn_mfma_f32_16x16x32_bf16(al, bh0, acc2[0], 0, 0, 0);
      acc2[1] = __builtin_amdgcn_mfma_f32_16x16x32_bf16(ah, bh1, acc2[1], 0, 0, 0);
      acc2[1] = __builtin_amdgcn_mfma_f32_16x16x32_bf16(ah, bl1, acc2[1], 0, 0, 0);
      acc2[1] = __builtin_amdgcn_mfma_f32_16x16x32_bf16(al, bh1, acc2[1], 0, 0, 0);
    }
  }

  // ---- epilogue: acc+bias -> GLOBAL S (m97-validated pattern; no LDS scatter) ----
  // C/D map (R10-verified): row = lk8*4+reg, col = n0w + nt*16 + lrow.
#pragma unroll
  for (int nt = 0; nt < 2; ++nt) {
    int n = n0w + nt * 16 + lrow;
    float bvT = bT[n], bvU = bU[n];
    int scolT = (n < 128) ? n : 256 + n;  // ts | uc
    int scolU = 128 + n;                  // tc | us
#pragma unroll
    for (int reg = 0; reg < 4; ++reg) {
      long grow = row0 + lk8 * 4 + reg;
      Sg[grow * 512 + scolT] = acc1[nt][reg] + bvT;
      Sg[grow * 512 + scolU] = acc2[nt][reg] + bvU;
    }
  }
}

// ---------------- kB: gates/mix/ff/LN from global S (R5 phases 3-5 verbatim) ----------------
// 256 threads, 8 rows/block, 32 KB LDS.

__launch_bounds__(256)
__global__ void k_gfl(const float* __restrict__ Sg, const char* __restrict__ wsb,
                      const float* __restrict__ tg_b, const float* __restrict__ ug_b,
                      const float* __restrict__ ff_b, const float* __restrict__ ln_g,
                      const float* __restrict__ ln_b, float* __restrict__ out) {
  __shared__ float lds[8 * 512 + 8 * 256 + 8 * 256];  // 32 KB
  float* S = lds;             // [8][512]
  float* F = lds + 4096;      // [8][256]
  float* H = lds + 6144;      // [8][256]

  const int t = threadIdx.x;
  const long row0 = (long)blockIdx.x * 8;

  // ---- stage S from global (coalesced) ----
  {
    const float4* g = (const float4*)(Sg + row0 * 512);
    float4* l = (float4*)S;
#pragma unroll
    for (int it = 0; it < 4; ++it) l[it * 256 + t] = g[it * 256 + t];
  }
  __syncthreads();

  // ---- phase 3: gates + mix (R5 verbatim) ----
  {
    int c = t & 127, half = t >> 7;
    const float4* W4 = (const float4*)(wsb + (half ? OFF_UG4 : OFF_TG4));
    const int so = half * 256;
    float acc[8];
#pragma unroll
    for (int r = 0; r < 8; ++r) acc[r] = 0.f;
    for (int j = 0; j < 256; j += 4) {
      float4 w = W4[(j >> 2) * 128 + c];
#pragma unroll
      for (int r = 0; r < 8; ++r) {
        float4 sv = *(const float4*)&S[r * 512 + so + j];
        acc[r] = fmaf(w.x, sv.x, acc[r]);
        acc[r] = fmaf(w.y, sv.y, acc[r]);
        acc[r] = fmaf(w.z, sv.z, acc[r]);
        acc[r] = fmaf(w.w, sv.w, acc[r]);
      }
    }
    float gb = half ? ug_b[c] : tg_b[c];
#pragma unroll
    for (int r = 0; r < 8; ++r) {
      float g = 1.f / (1.f + __expf(-(acc[r] + gb)));
      float a = S[r * 512 + so + c];
      float b = S[r * 512 + so + 128 + c];
      F[r * 256 + half * 128 + c] = fmaf(g, b - a, a);
    }
  }
  __syncthreads();

  // ---- phase 4: ff GEMM (R5 verbatim) ----
  {
    const float4* W4 = (const float4*)(wsb + OFF_FF4);
    float acc[8];
#pragma unroll
    for (int r = 0; r < 8; ++r) acc[r] = 0.f;
    for (int j = 0; j < 256; j += 4) {
      float4 w = W4[(j >> 2) * 256 + t];
#pragma unroll
      for (int r = 0; r < 8; ++r) {
        float4 fv = *(const float4*)&F[r * 256 + j];
        acc[r] = fmaf(w.x, fv.x, acc[r]);
        acc[r] = fmaf(w.y, fv.y, acc[r]);
        acc[r] = fmaf(w.z, fv.z, acc[r]);
        acc[r] = fmaf(w.w, fv.w, acc[r]);
      }
    }
    float bias = ff_b[t];
#pragma unroll
    for (int r = 0; r < 8; ++r) H[r * 256 + t] = acc[r] + bias;
  }
  __syncthreads();

  // ---- phase 5: LayerNorm + ReLU + store (R5 verbatim) ----
  {
    int r = t >> 5, q = t & 31;
    const float* Hr = H + r * 256 + q * 8;
    float s1 = 0.f, s2 = 0.f;
#pragma unroll
    for (int i = 0; i < 8; ++i) {
      float v = Hr[i];
      s1 += v;
      s2 += v * v;
    }
#pragma unroll
    for (int off = 1; off < 32; off <<= 1) {
      s1 += __shfl_xor(s1, off);
      s2 += __shfl_xor(s2, off);
    }
    float mu = s1 * (1.f / 256.f);
    float var = s2 * (1.f / 256.f) - mu * mu;
    float rstd = rsqrtf(var + 1e-5f);
    float* op = out + (row0 + r) * 256 + q * 8;
#pragma unroll
    for (int i = 0; i < 8; ++i) {
      float v = (Hr[i] - mu) * rstd * ln_g[q * 8 + i] + ln_b[q * 8 + i];
      op[i] = v > 0.f ? v : 0.f;
    }
  }
}

// ---------------- fallback: R5 fused scalar kernel (verbatim; known-pass 1338us) ----------------

__launch_bounds__(256)
__global__ void k_main5(const float* __restrict__ xt_g, const float* __restrict__ xu_g,
                        const char* __restrict__ wsb,
                        const float* __restrict__ tg_b, const float* __restrict__ ug_b,
                        const float* __restrict__ ff_b, const float* __restrict__ ln_g,
                        const float* __restrict__ ln_b, float* __restrict__ out) {
  __shared__ float lds[8 * 768 + 8 * 512 + 8 * 256];  // 48 KB
  float* xt = lds;
  float* S = lds + 8 * 768;
  float* xu = lds + 8 * 768 + 8 * 512;

  const int t = threadIdx.x;
  const long row0 = (long)blockIdx.x * 8;

  {
    const float4* g = (const float4*)(xt_g + row0 * 768);
    float4* l = (float4*)xt;
#pragma unroll
    for (int it = 0; it < 6; ++it) l[it * 256 + t] = g[it * 256 + t];
    const float4* gu = (const float4*)(xu_g + row0 * 256);
    float4* lu = (float4*)xu;
#pragma unroll
    for (int it = 0; it < 2; ++it) lu[it * 256 + t] = gu[it * 256 + t];
  }
  __syncthreads();

  {
    const float4* W4 = (const float4*)(wsb + OFF_MT4);
    float acc[8];
#pragma unroll
    for (int r = 0; r < 8; ++r) acc[r] = 0.f;
    for (int k = 0; k < 768; k += 4) {
      float4 w = W4[(k >> 2) * 256 + t];
#pragma unroll
      for (int r = 0; r < 8; ++r) {
        float4 xv = *(const float4*)&xt[r * 768 + k];
        acc[r] = fmaf(w.x, xv.x, acc[r]);
        acc[r] = fmaf(w.y, xv.y, acc[r]);
        acc[r] = fmaf(w.z, xv.z, acc[r]);
        acc[r] = fmaf(w.w, xv.w, acc[r]);
      }
    }
    float bias = ((const float*)(wsb + OFF_BT))[t];
    int d = (t < 128) ? t : (256 + t);
#pragma unroll
    for (int r = 0; r < 8; ++r) S[r * 512 + d] = acc[r] + bias;
  }

  {
    const float4* W4 = (const float4*)(wsb + OFF_MU4);
    float acc[8];
#pragma unroll
    for (int r = 0; r < 8; ++r) acc[r] = 0.f;
    for (int k = 0; k < 256; k += 4) {
      float4 w = W4[(k >> 2) * 256 + t];
#pragma unroll
      for (int r = 0; r < 8; ++r) {
        float4 xv = *(const float4*)&xu[r * 256 + k];
        acc[r] = fmaf(w.x, xv.x, acc[r]);
        acc[r] = fmaf(w.y, xv.y, acc[r]);
        acc[r] = fmaf(w.z, xv.z, acc[r]);
        acc[r] = fmaf(w.w, xv.w, acc[r]);
      }
    }
    float bias = ((const float*)(wsb + OFF_BU))[t];
#pragma unroll
    for (int r = 0; r < 8; ++r) S[r * 512 + 128 + t] = acc[r] + bias;
  }
  __syncthreads();

  {
    int c = t & 127, half = t >> 7;
    const float4* W4 = (const float4*)(wsb + (half ? OFF_UG4 : OFF_TG4));
    const int so = half * 256;
    float acc[8];
#pragma unroll
    for (int r = 0; r < 8; ++r) acc[r] = 0.f;
    for (int j = 0; j < 256; j += 4) {
      float4 w = W4[(j >> 2) * 128 + c];
#pragma unroll
      for (int r = 0; r < 8; ++r) {
        float4 sv = *(const float4*)&S[r * 512 + so + j];
        acc[r] = fmaf(w.x, sv.x, acc[r]);
        acc[r] = fmaf(w.y, sv.y, acc[r]);
        acc[r] = fmaf(w.z, sv.z, acc[r]);
        acc[r] = fmaf(w.w, sv.w, acc[r]);
      }
    }
    float gb = half ? ug_b[c] : tg_b[c];
    float* F = xu;
#pragma unroll
    for (int r = 0; r < 8; ++r) {
      float g = 1.f / (1.f + __expf(-(acc[r] + gb)));
      float a = S[r * 512 + so + c];
      float b = S[r * 512 + so + 128 + c];
      F[r * 256 + half * 128 + c] = fmaf(g, b - a, a);
    }
  }
  __syncthreads();

  {
    const float4* W4 = (const float4*)(wsb + OFF_FF4);
    const float* F = xu;
    float acc[8];
#pragma unroll
    for (int r = 0; r < 8; ++r) acc[r] = 0.f;
    for (int j = 0; j < 256; j += 4) {
      float4 w = W4[(j >> 2) * 256 + t];
#pragma unroll
      for (int r = 0; r < 8; ++r) {
        float4 fv = *(const float4*)&F[r * 256 + j];
        acc[r] = fmaf(w.x, fv.x, acc[r]);
        acc[r] = fmaf(w.y, fv.y, acc[r]);
        acc[r] = fmaf(w.z, fv.z, acc[r]);
        acc[r] = fmaf(w.w, fv.w, acc[r]);
      }
    }
    float* H = xt;
    float bias = ff_b[t];
#pragma unroll
    for (int r = 0; r < 8; ++r) H[r * 256 + t] = acc[r] + bias;
  }
  __syncthreads();

  {
    const float* H = xt;
    int r = t >> 5, q = t & 31;
    const float* Hr = H + r * 256 + q * 8;
    float s1 = 0.f, s2 = 0.f;
#pragma unroll
    for (int i = 0; i < 8; ++i) {
      float v = Hr[i];
      s1 += v;
      s2 += v * v;
    }
#pragma unroll
    for (int off = 1; off < 32; off <<= 1) {
      s1 += __shfl_xor(s1, off);
      s2 += __shfl_xor(s2, off);
    }
    float mu = s1 * (1.f / 256.f);
    float var = s2 * (1.f / 256.f) - mu * mu;
    float rstd = rsqrtf(var + 1e-5f);
    float* op = out + (row0 + r) * 256 + q * 8;
#pragma unroll
    for (int i = 0; i < 8; ++i) {
      float v = (Hr[i] - mu) * rstd * ln_g[q * 8 + i] + ln_b[q * 8 + i];
      op[i] = v > 0.f ? v : 0.f;
    }
  }
}

}  // namespace

extern "C" void kernel_launch(void* const* d_in, const int* in_sizes, int n_in,
                              void* d_out, int out_size, void* d_ws, size_t ws_size,
                              hipStream_t stream) {
  const float* text = (const float*)d_in[0];
  const float* user = (const float*)d_in[1];
  const float* tm_w = (const float*)d_in[2];
  const float* tm_b = (const float*)d_in[3];
  const float* um_w = (const float*)d_in[4];
  const float* um_b = (const float*)d_in[5];
  const float* ipw = (const float*)d_in[6];
  const float* ipb = (const float*)d_in[7];
  const float* opw = (const float*)d_in[8];
  const float* opb = (const float*)d_in[9];
  const float* tg_w = (const float*)d_in[10];
  const float* tg_b = (const float*)d_in[11];
  const float* ug_w = (const float*)d_in[12];
  const float* ug_b = (const float*)d_in[13];
  const float* ff_w = (const float*)d_in[14];
  const float* ff_b = (const float*)d_in[15];
  const float* ln_g = (const float*)d_in[16];
  const float* ln_b = (const float*)d_in[17];
  char* wsb = (char*)d_ws;
  float* out = (float*)d_out;

  // common precompute
  k_combine<<<256, 256, 0, stream>>>(ipw, opw, wsb);
  k_combine_bias<<<2, 256, 0, stream>>>(ipb, opb, opw, wsb);
  k_bias_tu<<<2, 256, 0, stream>>>(tm_b, um_b, wsb);
  k_transpose4<<<128, 256, 0, stream>>>(tg_w, (float*)(wsb + OFF_TG4), 128, 256);
  k_transpose4<<<128, 256, 0, stream>>>(ug_w, (float*)(wsb + OFF_UG4), 128, 256);
  k_transpose4<<<256, 256, 0, stream>>>(ff_w, (float*)(wsb + OFF_FF4), 256, 256);

  if ((long)ws_size >= WS_NEED) {
    // fast path: MFMA front -> global S -> scalar back
    float* Sg = (float*)(wsb + OFF_S);
    k_mt_hl<<<768, 256, 0, stream>>>(tm_w, wsb);
    k_mu_hl<<<256, 256, 0, stream>>>(um_w, wsb);
    k_s12<<<4096, 512, 0, stream>>>(text, user, wsb, Sg);
    k_gfl<<<8192, 256, 0, stream>>>(Sg, wsb, tg_b, ug_b, ff_b, ln_g, ln_b, out);
  } else {
    // fallback: R5 fused scalar (known-pass)
    k_mt4<<<768, 256, 0, stream>>>(tm_w, wsb);
    k_mu4<<<256, 256, 0, stream>>>(um_w, wsb);
    k_main5<<<8192, 256, 0, stream>>>(text, user, wsb, tg_b, ug_b, ff_b, ln_g, ln_b, out);
  }
}

// Round 14
// 547.675 us; speedup vs baseline: 4.0649x; 1.1807x over previous
//
#include <hip/hip_runtime.h>
#include <hip/hip_bf16.h>

// MultiViewFusion — two-kernel split, round 14: faster scalar back-end.
// Evidence ledger:
//   R5  PASS 0.0156 (1338us): scalar-f32 fused (folding algebra correct).
//   R6-R9 FAIL 0.13-0.17: any kernel where MFMA acc is scattered into LDS and
//        re-read. Quarantined: all MFMA results must exit via acc->global.
//   R10 PASS + zero poisons: MFMA stages 1/2 coordinate-exact vs scalar ref.
//   R13 PASS 0.0156 (646us): k_s12 (MFMA -> global S) + k_gfl (scalar back).
//        k_gfl=378us VALU-bound at 29% fp32 peak (1 col/thread: 8 ds_read per
//        32 FMA); k_s12~240us.
// R14: k_gfl2 = 2 adjacent cols/thread x 16 rows/block (R10-validated c0-pair
// structure): 8 ds_read per 64 FMA -> FMA-bound; weight L2 traffic halved.
// Gate weights in combined GW4 [j/4][256][4] pack (R9/R10-validated) at the
// old TG4/UG4 offsets; ws layout and WS_NEED unchanged. k_s12 verbatim.

namespace {

typedef __attribute__((ext_vector_type(8))) short short8v;   // 8 bf16 = 4 VGPR
typedef __attribute__((ext_vector_type(4))) float floatx4;   // MFMA C/D

// workspace byte offsets (unchanged from R13)
constexpr int OFF_CW  = 0;        // f32 CWt[4][128][128]
constexpr int OFF_CB  = 262144;   // f32 cv[4][128]
constexpr int OFF_BT  = 264192;   // f32 bT[256]  [ts|uc]
constexpr int OFF_BU  = 265216;   // f32 bU[256]  [tc|us]
constexpr int OFF_MTH = 266240;   // bf16 M_text hi packed [96][256][8]
constexpr int OFF_MTL = 659456;   // bf16 M_text lo
constexpr int OFF_MUH = 1052672;  // bf16 M_user hi packed [32][256][8]
constexpr int OFF_MUL = 1183744;  // bf16 M_user lo
constexpr int OFF_GW4 = 1314816;  // f32 gate W [64][256][4] (cols tg|ug)
constexpr int OFF_FW4 = 1576960;  // f32 ff  W  [64][256][4]
constexpr int OFF_MT4 = 1839104;  // f32 M_text pack [192][256][4]  (fallback)
constexpr int OFF_MU4 = 2625536;  // f32 M_user pack [64][256][4]   (fallback)
constexpr long OFF_S  = 2887680;  // f32 S [65536][512] = 134217728 B
constexpr long WS_NEED = OFF_S + 134217728L;

__device__ inline unsigned short f2b(float f) {
  __hip_bfloat16 h = __float2bfloat16(f);
  return __builtin_bit_cast(unsigned short, h);
}
__device__ inline float b2f(unsigned short u) {
  unsigned int v = ((unsigned int)u) << 16;
  return __builtin_bit_cast(float, v);
}
__device__ inline void split2(float v, unsigned short& h, unsigned short& l) {
  h = f2b(v);
  l = f2b(v - b2f(h));
}

// ---------------- precompute (tiny, L2-resident; validated) ----------------

__global__ void k_combine(const float* __restrict__ ipw, const float* __restrict__ opw,
                          char* __restrict__ wsb) {
  float* cw = (float*)(wsb + OFF_CW);
  int n = blockIdx.x * 256 + threadIdx.x;
  int i = n >> 14, o = (n >> 7) & 127, d = n & 127;
  const float* op = opw + i * 16384 + o * 128;
  const float* iv = ipw + i * 49152 + 256 * 128 + d;
  float s = 0.f;
#pragma unroll 4
  for (int m = 0; m < 128; ++m) s = fmaf(op[m], iv[m * 128], s);
  cw[i * 16384 + d * 128 + o] = s;
}

__global__ void k_combine_bias(const float* __restrict__ ipb, const float* __restrict__ opb,
                               const float* __restrict__ opw, char* __restrict__ wsb) {
  float* cb = (float*)(wsb + OFF_CB);
  int t = blockIdx.x * 256 + threadIdx.x;
  int i = t >> 7, o = t & 127;
  const float* op = opw + i * 16384 + o * 128;
  const float* ib = ipb + i * 384 + 256;
  float s = opb[i * 128 + o];
#pragma unroll 4
  for (int m = 0; m < 128; ++m) s = fmaf(op[m], ib[m], s);
  cb[t] = s;
}

// hi/lo bf16 pack for MFMA (fast path)
__global__ void k_mt_hl(const float* __restrict__ tm_w, char* __restrict__ wsb) {
  const float* cw = (const float*)(wsb + OFF_CW);
  unsigned short* dh = (unsigned short*)(wsb + OFF_MTH);
  unsigned short* dl = (unsigned short*)(wsb + OFF_MTL);
  int n = blockIdx.x * 256 + threadIdx.x;  // 768*256
  int k = n >> 8, c = n & 255;
  const float* p = cw + ((c >> 7) ? 3 : 0) * 16384 + (c & 127);
  float s = 0.f;
#pragma unroll 4
  for (int d = 0; d < 128; ++d) s = fmaf(p[d * 128], tm_w[d * 768 + k], s);
  unsigned short h, l;
  split2(s, h, l);
  int ofs = (((k >> 3) * 256 + c) << 3) + (k & 7);
  dh[ofs] = h;
  dl[ofs] = l;
}

__global__ void k_mu_hl(const float* __restrict__ um_w, char* __restrict__ wsb) {
  const float* cw = (const float*)(wsb + OFF_CW);
  unsigned short* dh = (unsigned short*)(wsb + OFF_MUH);
  unsigned short* dl = (unsigned short*)(wsb + OFF_MUL);
  int n = blockIdx.x * 256 + threadIdx.x;  // 256*256
  int k = n >> 8, c = n & 255;
  const float* p = cw + ((c >> 7) ? 1 : 2) * 16384 + (c & 127);
  float s = 0.f;
#pragma unroll 4
  for (int d = 0; d < 128; ++d) s = fmaf(p[d * 128], um_w[d * 256 + k], s);
  unsigned short h, l;
  split2(s, h, l);
  int ofs = (((k >> 3) * 256 + c) << 3) + (k & 7);
  dh[ofs] = h;
  dl[ofs] = l;
}

// f32 [K/4][256][4] packs (fallback scalar path)
__global__ void k_mt4(const float* __restrict__ tm_w, char* __restrict__ wsb) {
  const float* cw = (const float*)(wsb + OFF_CW);
  float* dst = (float*)(wsb + OFF_MT4);
  int n = blockIdx.x * 256 + threadIdx.x;  // 768*256
  int k = n >> 8, c = n & 255;
  const float* p = cw + ((c >> 7) ? 3 : 0) * 16384 + (c & 127);
  float s = 0.f;
#pragma unroll 4
  for (int d = 0; d < 128; ++d) s = fmaf(p[d * 128], tm_w[d * 768 + k], s);
  dst[(((k >> 2) * 256 + c) << 2) + (k & 3)] = s;
}

__global__ void k_mu4(const float* __restrict__ um_w, char* __restrict__ wsb) {
  const float* cw = (const float*)(wsb + OFF_CW);
  float* dst = (float*)(wsb + OFF_MU4);
  int n = blockIdx.x * 256 + threadIdx.x;  // 256*256
  int k = n >> 8, c = n & 255;
  const float* p = cw + ((c >> 7) ? 1 : 2) * 16384 + (c & 127);
  float s = 0.f;
#pragma unroll 4
  for (int d = 0; d < 128; ++d) s = fmaf(p[d * 128], um_w[d * 256 + k], s);
  dst[(((k >> 2) * 256 + c) << 2) + (k & 3)] = s;
}

__global__ void k_bias_tu(const float* __restrict__ tm_b, const float* __restrict__ um_b,
                          char* __restrict__ wsb) {
  const float* cw = (const float*)(wsb + OFF_CW);
  const float* cb = (const float*)(wsb + OFF_CB);
  float* bT = (float*)(wsb + OFF_BT);
  float* bU = (float*)(wsb + OFF_BU);
  int t = blockIdx.x * 256 + threadIdx.x;
  if (t < 256) {
    int sel = (t >> 7) ? 3 : 0;
    const float* p = cw + sel * 16384 + (t & 127);
    float s = cb[sel * 128 + (t & 127)];
#pragma unroll 4
    for (int d = 0; d < 128; ++d) s = fmaf(p[d * 128], tm_b[d], s);
    bT[t] = s;
  } else {
    int c = t - 256;
    int sel = (c >> 7) ? 1 : 2;
    const float* p = cw + sel * 16384 + (c & 127);
    float s = cb[sel * 128 + (c & 127)];
#pragma unroll 4
    for (int d = 0; d < 128; ++d) s = fmaf(p[d * 128], um_b[d], s);
    bU[c] = s;
  }
}

// combined gate pack (R9/R10-validated): cols 0..127 = tg_w, 128..255 = ug_w
__global__ void k_pack_gw4(const float* __restrict__ tg_w, const float* __restrict__ ug_w,
                           char* __restrict__ wsb) {
  float* dst = (float*)(wsb + OFF_GW4);
  int idx = blockIdx.x * 256 + threadIdx.x;  // 65536
  int j = idx >> 8, n = idx & 255;
  float v = (n < 128) ? tg_w[n * 256 + j] : ug_w[(n - 128) * 256 + j];
  dst[(((j >> 2) * 256 + n) << 2) + (j & 3)] = v;
}

// dst[((k>>2)*R + o)*4 + (k&3)] = src[o*C + k]
__global__ void k_transpose4(const float* __restrict__ src, float* __restrict__ dst,
                             int R, int C) {
  int n = blockIdx.x * 256 + threadIdx.x;
  if (n >= R * C) return;
  int o = n / C, k = n % C;
  dst[(((k >> 2) * R + o) << 2) + (k & 3)] = src[n];
}

// ---------------- kA: MFMA stages 1/2 -> global S (R13-verbatim, validated) ----------------
// 512 threads = 8 waves, 16 rows/block, 64 KB LDS.

#define SWZ(byte, row) ((byte) ^ (((row) & 7) << 4))

__launch_bounds__(512)
__global__ void k_s12(const float* __restrict__ xt_g, const float* __restrict__ xu_g,
                      const char* __restrict__ wsb, float* __restrict__ Sg) {
  __shared__ __align__(16) char sm[65536];
  constexpr int XTL = 24576, XUH = 49152, XUL = 57344;

  const int t = threadIdx.x;
  const int wave = t >> 6, lane = t & 63;
  const int lrow = lane & 15;
  const int lk8 = lane >> 4;
  const int n0w = wave * 32;
  const long row0 = (long)blockIdx.x * 16;

  const float* bT = (const float*)(wsb + OFF_BT);
  const float* bU = (const float*)(wsb + OFF_BU);

  // ---- staging hi/lo (R10-validated) ----
  {
    const float4* gx = (const float4*)(xt_g + row0 * 768);
#pragma unroll
    for (int it = 0; it < 6; ++it) {
      int idx = it * 512 + t;
      float4 v = gx[idx];
      int row = idx / 192, rem = idx - row * 192;
      int b0 = row * 1536 + rem * 8;
      ushort4 hh, ll;
      split2(v.x, hh.x, ll.x); split2(v.y, hh.y, ll.y);
      split2(v.z, hh.z, ll.z); split2(v.w, hh.w, ll.w);
      *(ushort4*)(sm + SWZ(b0, row)) = hh;
      *(ushort4*)(sm + XTL + SWZ(b0, row)) = ll;
    }
    const float4* gu = (const float4*)(xu_g + row0 * 256);
#pragma unroll
    for (int it = 0; it < 2; ++it) {
      int idx = it * 512 + t;
      float4 v = gu[idx];
      int row = idx >> 6, rem = idx & 63;
      int b0 = row * 512 + rem * 8;
      ushort4 hh, ll;
      split2(v.x, hh.x, ll.x); split2(v.y, hh.y, ll.y);
      split2(v.z, hh.z, ll.z); split2(v.w, hh.w, ll.w);
      *(ushort4*)(sm + XUH + SWZ(b0, row)) = hh;
      *(ushort4*)(sm + XUL + SWZ(b0, row)) = ll;
    }
  }
  __syncthreads();

  floatx4 zero = {0.f, 0.f, 0.f, 0.f};

  // ---- stage 1: text GEMM K=768, 3-term hi/lo split ----
  floatx4 acc1[2] = {zero, zero};
  {
    const char* wh = wsb + OFF_MTH;
    const char* wl = wsb + OFF_MTL;
#pragma unroll 4
    for (int k0 = 0; k0 < 768; k0 += 32) {
      int kb = (k0 + lk8 * 8) * 2;
      short8v ah = *(const short8v*)(sm + SWZ(lrow * 1536 + kb, lrow));
      short8v al = *(const short8v*)(sm + XTL + SWZ(lrow * 1536 + kb, lrow));
      int k8 = (k0 >> 3) + lk8;
      int o0 = (k8 * 256 + n0w + lrow) << 4;
      int o1 = (k8 * 256 + n0w + 16 + lrow) << 4;
      short8v bh0 = *(const short8v*)(wh + o0);
      short8v bh1 = *(const short8v*)(wh + o1);
      short8v bl0 = *(const short8v*)(wl + o0);
      short8v bl1 = *(const short8v*)(wl + o1);
      acc1[0] = __builtin_amdgcn_mfma_f32_16x16x32_bf16(ah, bh0, acc1[0], 0, 0, 0);
      acc1[0] = __builtin_amdgcn_mfma_f32_16x16x32_bf16(ah, bl0, acc1[0], 0, 0, 0);
      acc1[0] = __builtin_amdgcn_mfma_f32_16x16x32_bf16(al, bh0, acc1[0], 0, 0, 0);
      acc1[1] = __builtin_amdgcn_mfma_f32_16x16x32_bf16(ah, bh1, acc1[1], 0, 0, 0);
      acc1[1] = __builtin_amdgcn_mfma_f32_16x16x32_bf16(ah, bl1, acc1[1], 0, 0, 0);
      acc1[1] = __builtin_amdgcn_mfma_f32_16x16x32_bf16(al, bh1, acc1[1], 0, 0, 0);
    }
  }

  // ---- stage 2: user GEMM K=256 ----
  floatx4 acc2[2] = {zero, zero};
  {
    const char* wh = wsb + OFF_MUH;
    const char* wl = wsb + OFF_MUL;
#pragma unroll
    for (int k0 = 0; k0 < 256; k0 += 32) {
      int kb = (k0 + lk8 * 8) * 2;
      short8v ah = *(const short8v*)(sm + XUH + SWZ(lrow * 512 + kb, lrow));
      short8v al = *(const short8v*)(sm + XUL + SWZ(lrow * 512 + kb, lrow));
      int k8 = (k0 >> 3) + lk8;
      int o0 = (k8 * 256 + n0w + lrow) << 4;
      int o1 = (k8 * 256 + n0w + 16 + lrow) << 4;
      short8v bh0 = *(const short8v*)(wh + o0);
      short8v bh1 = *(const short8v*)(wh + o1);
      short8v bl0 = *(const short8v*)(wl + o0);
      short8v bl1 = *(const short8v*)(wl + o1);
      acc2[0] = __builtin_amdgcn_mfma_f32_16x16x32_bf16(ah, bh0, acc2[0], 0, 0, 0);
      acc2[0] = __builtin_amdgcn_mfma_f32_16x16x32_bf16(ah, bl0, acc2[0], 0, 0, 0);
      acc2[0] = __builtin_amdgcn_mfma_f32_16x16x32_bf16(al, bh0, acc2[0], 0, 0, 0);
      acc2[1] = __builtin_amdgcn_mfma_f32_16x16x32_bf16(ah, bh1, acc2[1], 0, 0, 0);
      acc2[1] = __builtin_amdgcn_mfma_f32_16x16x32_bf16(ah, bl1, acc2[1], 0, 0, 0);
      acc2[1] = __builtin_amdgcn_mfma_f32_16x16x32_bf16(al, bh1, acc2[1], 0, 0, 0);
    }
  }

  // ---- epilogue: acc+bias -> GLOBAL S (quarantine-compliant) ----
#pragma unroll
  for (int nt = 0; nt < 2; ++nt) {
    int n = n0w + nt * 16 + lrow;
    float bvT = bT[n], bvU = bU[n];
    int scolT = (n < 128) ? n : 256 + n;  // ts | uc
    int scolU = 128 + n;                  // tc | us
#pragma unroll
    for (int reg = 0; reg < 4; ++reg) {
      long grow = row0 + lk8 * 4 + reg;
      Sg[grow * 512 + scolT] = acc1[nt][reg] + bvT;
      Sg[grow * 512 + scolU] = acc2[nt][reg] + bvU;
    }
  }
}

// ---------------- kB: gates/mix/ff/LN from global S — 2 cols/thread ----------------
// 256 threads, 16 rows/block (4096 blocks), 48 KB LDS.
// thread: rh = t>>7 (8-row half), c0 = (t&127)*2 (adjacent col pair).
// Per j-step: 8 broadcast ds_read + 64 FMA (FMA-bound vs R13's 8:32).

__launch_bounds__(256)
__global__ void k_gfl2(const float* __restrict__ Sg, const char* __restrict__ wsb,
                       const float* __restrict__ tg_b, const float* __restrict__ ug_b,
                       const float* __restrict__ ff_b, const float* __restrict__ ln_g,
                       const float* __restrict__ ln_b, float* __restrict__ out) {
  __shared__ float lds[16 * 512 + 16 * 256];  // S 32KB + F 16KB = 48KB
  float* S = lds;             // [16][512]
  float* F = lds + 8192;      // [16][256]
  float* H = lds;             // [16][256] overlays S (dead after phase 3)

  const int t = threadIdx.x;
  const long row0 = (long)blockIdx.x * 16;

  // ---- stage S from global (coalesced): 16*512 floats = 2048 float4 ----
  {
    const float4* g = (const float4*)(Sg + row0 * 512);
    float4* l = (float4*)S;
#pragma unroll
    for (int it = 0; it < 8; ++it) l[it * 256 + t] = g[it * 256 + t];
  }
  __syncthreads();

  const int rh = t >> 7, c0 = (t & 127) * 2;
  const int r0 = rh * 8;

  // ---- phase 3: gates + mix -> F ----
  {
    const int so3 = (c0 < 128) ? 0 : 256;  // tg: S[0:256]=[ts|tc]; ug: S[256:512]=[us|uc]
    const float4* GW = (const float4*)(wsb + OFF_GW4);
    float acc[8][2] = {};
    for (int j = 0; j < 256; j += 4) {
      float4 w0 = GW[(j >> 2) * 256 + c0];
      float4 w1 = GW[(j >> 2) * 256 + c0 + 1];
#pragma unroll
      for (int r = 0; r < 8; ++r) {
        float4 sv = *(const float4*)&S[(r0 + r) * 512 + so3 + j];  // wave-uniform broadcast
        acc[r][0] = fmaf(sv.x, w0.x, fmaf(sv.y, w0.y, fmaf(sv.z, w0.z, fmaf(sv.w, w0.w, acc[r][0]))));
        acc[r][1] = fmaf(sv.x, w1.x, fmaf(sv.y, w1.y, fmaf(sv.z, w1.z, fmaf(sv.w, w1.w, acc[r][1]))));
      }
    }
    float gb0 = (c0 < 128) ? tg_b[c0] : ug_b[c0 - 128];
    float gb1 = (c0 < 128) ? tg_b[c0 + 1] : ug_b[c0 - 127];
    int am = (c0 < 128) ? c0 : 128 + c0;  // self col in S
#pragma unroll
    for (int r = 0; r < 8; ++r) {
      int row = r0 + r;
      float g0 = 1.f / (1.f + __expf(-(acc[r][0] + gb0)));
      float g1 = 1.f / (1.f + __expf(-(acc[r][1] + gb1)));
      float a0 = S[row * 512 + am],     b0v = S[row * 512 + am + 128];
      float a1 = S[row * 512 + am + 1], b1v = S[row * 512 + am + 129];
      F[row * 256 + c0]     = fmaf(g0, b0v - a0, a0);
      F[row * 256 + c0 + 1] = fmaf(g1, b1v - a1, a1);
    }
  }
  __syncthreads();

  // ---- phase 4: ff GEMM -> H (overlays dead S) ----
  {
    const float4* FW = (const float4*)(wsb + OFF_FW4);
    float acc[8][2] = {};
    for (int j = 0; j < 256; j += 4) {
      float4 w0 = FW[(j >> 2) * 256 + c0];
      float4 w1 = FW[(j >> 2) * 256 + c0 + 1];
#pragma unroll
      for (int r = 0; r < 8; ++r) {
        float4 fv = *(const float4*)&F[(r0 + r) * 256 + j];  // broadcast
        acc[r][0] = fmaf(fv.x, w0.x, fmaf(fv.y, w0.y, fmaf(fv.z, w0.z, fmaf(fv.w, w0.w, acc[r][0]))));
        acc[r][1] = fmaf(fv.x, w1.x, fmaf(fv.y, w1.y, fmaf(fv.z, w1.z, fmaf(fv.w, w1.w, acc[r][1]))));
      }
    }
    float fb0 = ff_b[c0], fb1 = ff_b[c0 + 1];
#pragma unroll
    for (int r = 0; r < 8; ++r) {
      int row = r0 + r;
      H[row * 256 + c0]     = acc[r][0] + fb0;
      H[row * 256 + c0 + 1] = acc[r][1] + fb1;
    }
  }
  __syncthreads();

  // ---- phase 5: LayerNorm + ReLU + store. 16 threads/row, 16 elems each ----
  {
    int r = t >> 4, q = t & 15;
    const float* Hr = H + r * 256 + q * 16;
    float4 hv[4];
    float s1 = 0.f, s2 = 0.f;
#pragma unroll
    for (int j = 0; j < 4; ++j) {
      hv[j] = *(const float4*)(Hr + j * 4);
      s1 += hv[j].x + hv[j].y + hv[j].z + hv[j].w;
      s2 += hv[j].x * hv[j].x + hv[j].y * hv[j].y + hv[j].z * hv[j].z + hv[j].w * hv[j].w;
    }
#pragma unroll
    for (int off = 1; off < 16; off <<= 1) {
      s1 += __shfl_xor(s1, off);
      s2 += __shfl_xor(s2, off);
    }
    float mu = s1 * (1.f / 256.f);
    float var = s2 * (1.f / 256.f) - mu * mu;
    float rstd = rsqrtf(var + 1e-5f);
    float* op = out + (row0 + r) * 256 + q * 16;
#pragma unroll
    for (int j = 0; j < 4; ++j) {
      const float* gp = ln_g + q * 16 + j * 4;
      const float* bp = ln_b + q * 16 + j * 4;
      float4 o;
      o.x = fmaf((hv[j].x - mu) * rstd, gp[0], bp[0]);
      o.y = fmaf((hv[j].y - mu) * rstd, gp[1], bp[1]);
      o.z = fmaf((hv[j].z - mu) * rstd, gp[2], bp[2]);
      o.w = fmaf((hv[j].w - mu) * rstd, gp[3], bp[3]);
      o.x = o.x > 0.f ? o.x : 0.f;
      o.y = o.y > 0.f ? o.y : 0.f;
      o.z = o.z > 0.f ? o.z : 0.f;
      o.w = o.w > 0.f ? o.w : 0.f;
      *(float4*)(op + j * 4) = o;
    }
  }
}

// ---------------- fallback: R5 fused scalar kernel (GW4-adapted) ----------------

__launch_bounds__(256)
__global__ void k_main5(const float* __restrict__ xt_g, const float* __restrict__ xu_g,
                        const char* __restrict__ wsb,
                        const float* __restrict__ tg_b, const float* __restrict__ ug_b,
                        const float* __restrict__ ff_b, const float* __restrict__ ln_g,
                        const float* __restrict__ ln_b, float* __restrict__ out) {
  __shared__ float lds[8 * 768 + 8 * 512 + 8 * 256];  // 48 KB
  float* xt = lds;
  float* S = lds + 8 * 768;
  float* xu = lds + 8 * 768 + 8 * 512;

  const int t = threadIdx.x;
  const long row0 = (long)blockIdx.x * 8;

  {
    const float4* g = (const float4*)(xt_g + row0 * 768);
    float4* l = (float4*)xt;
#pragma unroll
    for (int it = 0; it < 6; ++it) l[it * 256 + t] = g[it * 256 + t];
    const float4* gu = (const float4*)(xu_g + row0 * 256);
    float4* lu = (float4*)xu;
#pragma unroll
    for (int it = 0; it < 2; ++it) lu[it * 256 + t] = gu[it * 256 + t];
  }
  __syncthreads();

  {
    const float4* W4 = (const float4*)(wsb + OFF_MT4);
    float acc[8];
#pragma unroll
    for (int r = 0; r < 8; ++r) acc[r] = 0.f;
    for (int k = 0; k < 768; k += 4) {
      float4 w = W4[(k >> 2) * 256 + t];
#pragma unroll
      for (int r = 0; r < 8; ++r) {
        float4 xv = *(const float4*)&xt[r * 768 + k];
        acc[r] = fmaf(w.x, xv.x, acc[r]);
        acc[r] = fmaf(w.y, xv.y, acc[r]);
        acc[r] = fmaf(w.z, xv.z, acc[r]);
        acc[r] = fmaf(w.w, xv.w, acc[r]);
      }
    }
    float bias = ((const float*)(wsb + OFF_BT))[t];
    int d = (t < 128) ? t : (256 + t);
#pragma unroll
    for (int r = 0; r < 8; ++r) S[r * 512 + d] = acc[r] + bias;
  }

  {
    const float4* W4 = (const float4*)(wsb + OFF_MU4);
    float acc[8];
#pragma unroll
    for (int r = 0; r < 8; ++r) acc[r] = 0.f;
    for (int k = 0; k < 256; k += 4) {
      float4 w = W4[(k >> 2) * 256 + t];
#pragma unroll
      for (int r = 0; r < 8; ++r) {
        float4 xv = *(const float4*)&xu[r * 256 + k];
        acc[r] = fmaf(w.x, xv.x, acc[r]);
        acc[r] = fmaf(w.y, xv.y, acc[r]);
        acc[r] = fmaf(w.z, xv.z, acc[r]);
        acc[r] = fmaf(w.w, xv.w, acc[r]);
      }
    }
    float bias = ((const float*)(wsb + OFF_BU))[t];
#pragma unroll
    for (int r = 0; r < 8; ++r) S[r * 512 + 128 + t] = acc[r] + bias;
  }
  __syncthreads();

  {
    int c = t & 127, half = t >> 7;
    const float4* W4 = (const float4*)(wsb + OFF_GW4);
    const int wcol = half * 128 + c;  // combined [tg|ug] pack
    const int so = half * 256;
    float acc[8];
#pragma unroll
    for (int r = 0; r < 8; ++r) acc[r] = 0.f;
    for (int j = 0; j < 256; j += 4) {
      float4 w = W4[(j >> 2) * 256 + wcol];
#pragma unroll
      for (int r = 0; r < 8; ++r) {
        float4 sv = *(const float4*)&S[r * 512 + so + j];
        acc[r] = fmaf(w.x, sv.x, acc[r]);
        acc[r] = fmaf(w.y, sv.y, acc[r]);
        acc[r] = fmaf(w.z, sv.z, acc[r]);
        acc[r] = fmaf(w.w, sv.w, acc[r]);
      }
    }
    float gb = half ? ug_b[c] : tg_b[c];
    float* F = xu;
#pragma unroll
    for (int r = 0; r < 8; ++r) {
      float g = 1.f / (1.f + __expf(-(acc[r] + gb)));
      float a = S[r * 512 + so + c];
      float b = S[r * 512 + so + 128 + c];
      F[r * 256 + half * 128 + c] = fmaf(g, b - a, a);
    }
  }
  __syncthreads();

  {
    const float4* W4 = (const float4*)(wsb + OFF_FW4);
    const float* F = xu;
    float acc[8];
#pragma unroll
    for (int r = 0; r < 8; ++r) acc[r] = 0.f;
    for (int j = 0; j < 256; j += 4) {
      float4 w = W4[(j >> 2) * 256 + t];
#pragma unroll
      for (int r = 0; r < 8; ++r) {
        float4 fv = *(const float4*)&F[r * 256 + j];
        acc[r] = fmaf(w.x, fv.x, acc[r]);
        acc[r] = fmaf(w.y, fv.y, acc[r]);
        acc[r] = fmaf(w.z, fv.z, acc[r]);
        acc[r] = fmaf(w.w, fv.w, acc[r]);
      }
    }
    float* H = xt;
    float bias = ff_b[t];
#pragma unroll
    for (int r = 0; r < 8; ++r) H[r * 256 + t] = acc[r] + bias;
  }
  __syncthreads();

  {
    const float* H = xt;
    int r = t >> 5, q = t & 31;
    const float* Hr = H + r * 256 + q * 8;
    float s1 = 0.f, s2 = 0.f;
#pragma unroll
    for (int i = 0; i < 8; ++i) {
      float v = Hr[i];
      s1 += v;
      s2 += v * v;
    }
#pragma unroll
    for (int off = 1; off < 32; off <<= 1) {
      s1 += __shfl_xor(s1, off);
      s2 += __shfl_xor(s2, off);
    }
    float mu = s1 * (1.f / 256.f);
    float var = s2 * (1.f / 256.f) - mu * mu;
    float rstd = rsqrtf(var + 1e-5f);
    float* op = out + (row0 + r) * 256 + q * 8;
#pragma unroll
    for (int i = 0; i < 8; ++i) {
      float v = (Hr[i] - mu) * rstd * ln_g[q * 8 + i] + ln_b[q * 8 + i];
      op[i] = v > 0.f ? v : 0.f;
    }
  }
}

}  // namespace

extern "C" void kernel_launch(void* const* d_in, const int* in_sizes, int n_in,
                              void* d_out, int out_size, void* d_ws, size_t ws_size,
                              hipStream_t stream) {
  const float* text = (const float*)d_in[0];
  const float* user = (const float*)d_in[1];
  const float* tm_w = (const float*)d_in[2];
  const float* tm_b = (const float*)d_in[3];
  const float* um_w = (const float*)d_in[4];
  const float* um_b = (const float*)d_in[5];
  const float* ipw = (const float*)d_in[6];
  const float* ipb = (const float*)d_in[7];
  const float* opw = (const float*)d_in[8];
  const float* opb = (const float*)d_in[9];
  const float* tg_w = (const float*)d_in[10];
  const float* tg_b = (const float*)d_in[11];
  const float* ug_w = (const float*)d_in[12];
  const float* ug_b = (const float*)d_in[13];
  const float* ff_w = (const float*)d_in[14];
  const float* ff_b = (const float*)d_in[15];
  const float* ln_g = (const float*)d_in[16];
  const float* ln_b = (const float*)d_in[17];
  char* wsb = (char*)d_ws;
  float* out = (float*)d_out;

  // common precompute
  k_combine<<<256, 256, 0, stream>>>(ipw, opw, wsb);
  k_combine_bias<<<2, 256, 0, stream>>>(ipb, opb, opw, wsb);
  k_bias_tu<<<2, 256, 0, stream>>>(tm_b, um_b, wsb);
  k_pack_gw4<<<256, 256, 0, stream>>>(tg_w, ug_w, wsb);
  k_transpose4<<<256, 256, 0, stream>>>(ff_w, (float*)(wsb + OFF_FW4), 256, 256);

  if ((long)ws_size >= WS_NEED) {
    // fast path: MFMA front -> global S -> 2-col scalar back
    float* Sg = (float*)(wsb + OFF_S);
    k_mt_hl<<<768, 256, 0, stream>>>(tm_w, wsb);
    k_mu_hl<<<256, 256, 0, stream>>>(um_w, wsb);
    k_s12<<<4096, 512, 0, stream>>>(text, user, wsb, Sg);
    k_gfl2<<<4096, 256, 0, stream>>>(Sg, wsb, tg_b, ug_b, ff_b, ln_g, ln_b, out);
  } else {
    // fallback: R5 fused scalar (known-pass)
    k_mt4<<<768, 256, 0, stream>>>(tm_w, wsb);
    k_mu4<<<256, 256, 0, stream>>>(um_w, wsb);
    k_main5<<<8192, 256, 0, stream>>>(text, user, wsb, tg_b, ug_b, ff_b, ln_g, ln_b, out);
  }
}